// Round 1
// baseline (2432.751 us; speedup 1.0000x reference)
//
#include <hip/hip_runtime.h>
#include <math.h>

// Problem constants
static constexpr int Bsz = 4;
static constexpr int Tn  = 2048;
static constexpr int Cn  = 1024;
static constexpr int Hn  = 16;
static constexpr int Dn  = 64;   // head dim

// ---------------------------------------------------------------------------
// Generic fp32 GEMM: out = A[M,K] @ W[K,N] + bias[N]
// OUT_HEADS=1: out index ((b*H+h)*T+t)*D+d  (head-split layout for Q/K/V)
// OUT_HEADS=0: out index m*N+n              (plain layout)
// Tile 64x64, 256 threads (16x16), each thread 4x4, BK=16.
// ---------------------------------------------------------------------------
template<int OUT_HEADS>
__global__ __launch_bounds__(256) void gemm_bias_k(
    const float* __restrict__ A, const float* __restrict__ W,
    const float* __restrict__ bias, float* __restrict__ out) {
  constexpr int Kdim = Cn, Ndim = Cn;
  __shared__ float As[16][68];   // [k][m], row stride 68 floats (272B, 16B-aligned)
  __shared__ float Ws[16][68];   // [k][n]
  const int tid = threadIdx.x;
  const int tx = tid & 15, ty = tid >> 4;
  const int row0 = blockIdx.y * 64;
  const int col0 = blockIdx.x * 64;
  // staging indices
  const int ar = tid >> 2;         // 0..63 row within A tile
  const int ak = (tid & 3) * 4;    // k offset (float4)
  const int wr = tid >> 4;         // 0..15 k row of W tile
  const int wc = (tid & 15) * 4;   // col offset (float4)

  float acc[4][4] = {};

  for (int k0 = 0; k0 < Kdim; k0 += 16) {
    float4 av = *reinterpret_cast<const float4*>(&A[(size_t)(row0 + ar) * Kdim + k0 + ak]);
    float4 wv = *reinterpret_cast<const float4*>(&W[(size_t)(k0 + wr) * Ndim + col0 + wc]);
    As[ak + 0][ar] = av.x;
    As[ak + 1][ar] = av.y;
    As[ak + 2][ar] = av.z;
    As[ak + 3][ar] = av.w;
    *reinterpret_cast<float4*>(&Ws[wr][wc]) = wv;
    __syncthreads();
#pragma unroll
    for (int kk = 0; kk < 16; ++kk) {
      const float4 a4 = *reinterpret_cast<const float4*>(&As[kk][ty * 4]);
      const float4 w4 = *reinterpret_cast<const float4*>(&Ws[kk][tx * 4]);
      const float a[4] = {a4.x, a4.y, a4.z, a4.w};
      const float w[4] = {w4.x, w4.y, w4.z, w4.w};
#pragma unroll
      for (int i = 0; i < 4; ++i)
#pragma unroll
        for (int j = 0; j < 4; ++j)
          acc[i][j] = fmaf(a[i], w[j], acc[i][j]);
    }
    __syncthreads();
  }

#pragma unroll
  for (int i = 0; i < 4; ++i) {
    const int row = row0 + ty * 4 + i;      // = b*T + t
    float4 o4;
    o4.x = acc[i][0] + bias[col0 + tx * 4 + 0];
    o4.y = acc[i][1] + bias[col0 + tx * 4 + 1];
    o4.z = acc[i][2] + bias[col0 + tx * 4 + 2];
    o4.w = acc[i][3] + bias[col0 + tx * 4 + 3];
    float* po;
    if (OUT_HEADS) {
      const int bb = row / Tn, t = row % Tn;
      const int h = col0 / Dn;              // col0 is a multiple of 64 == D
      po = &out[(((size_t)bb * Hn + h) * Tn + t) * Dn + tx * 4];
    } else {
      po = &out[(size_t)row * Ndim + col0 + tx * 4];
    }
    *reinterpret_cast<float4*>(po) = o4;
  }
}

// ---------------------------------------------------------------------------
// Flash-style causal attention, fp32.
// Q,K,V: [B,H,T,D].  Y: [B,T,C] (heads re-interleaved).
// Grid: (T/64, B*H). Block 256 threads (16x16), each thread 4x4 of the
// 64(q-rows) x 64(D) output accumulator; S tiles 64x64 computed per KV tile.
// ---------------------------------------------------------------------------
__global__ __launch_bounds__(256) void attn_k(
    const float* __restrict__ Q, const float* __restrict__ K,
    const float* __restrict__ V, float* __restrict__ Y) {
  __shared__ float Qs[64][68];
  __shared__ float Ks[64][68];
  __shared__ float Vs[64][68];
  __shared__ float Ps[64][68];
  const int tid = threadIdx.x;
  const int tx = tid & 15, ty = tid >> 4;
  const int qt = blockIdx.x;     // q tile index, 0..31
  const int bh = blockIdx.y;     // 0..63
  const float* Qp = Q + (size_t)bh * Tn * Dn + (size_t)qt * 64 * Dn;
  const float* Kp = K + (size_t)bh * Tn * Dn;
  const float* Vp = V + (size_t)bh * Tn * Dn;

  // load Q tile (64x64 floats)
  {
    const int c = (tid & 15) * 4;
#pragma unroll
    for (int p = 0; p < 4; ++p) {
      const int r = p * 16 + (tid >> 4);
      *reinterpret_cast<float4*>(&Qs[r][c]) =
          *reinterpret_cast<const float4*>(&Qp[r * Dn + c]);
    }
  }

  float o[4][4] = {};
  float m_run[4], l_run[4];
#pragma unroll
  for (int i = 0; i < 4; ++i) { m_run[i] = -INFINITY; l_run[i] = 0.f; }
  const float scale = 0.125f;  // 1/sqrt(64)

  for (int kt = 0; kt <= qt; ++kt) {
    // stage K and V tiles
    {
      const int c = (tid & 15) * 4;
#pragma unroll
      for (int p = 0; p < 4; ++p) {
        const int r = p * 16 + (tid >> 4);
        *reinterpret_cast<float4*>(&Ks[r][c]) =
            *reinterpret_cast<const float4*>(&Kp[(size_t)(kt * 64 + r) * Dn + c]);
        *reinterpret_cast<float4*>(&Vs[r][c]) =
            *reinterpret_cast<const float4*>(&Vp[(size_t)(kt * 64 + r) * Dn + c]);
      }
    }
    __syncthreads();

    // S = Q . K^T  (each thread: rows ty*4+i, cols tx*4+j)
    float s[4][4] = {};
#pragma unroll
    for (int d4 = 0; d4 < 16; ++d4) {
      float4 qa[4], kb[4];
#pragma unroll
      for (int i = 0; i < 4; ++i)
        qa[i] = *reinterpret_cast<const float4*>(&Qs[ty * 4 + i][d4 * 4]);
#pragma unroll
      for (int j = 0; j < 4; ++j)
        kb[j] = *reinterpret_cast<const float4*>(&Ks[tx * 4 + j][d4 * 4]);
#pragma unroll
      for (int i = 0; i < 4; ++i)
#pragma unroll
        for (int j = 0; j < 4; ++j) {
          s[i][j] = fmaf(qa[i].x, kb[j].x, s[i][j]);
          s[i][j] = fmaf(qa[i].y, kb[j].y, s[i][j]);
          s[i][j] = fmaf(qa[i].z, kb[j].z, s[i][j]);
          s[i][j] = fmaf(qa[i].w, kb[j].w, s[i][j]);
        }
    }

    // scale + causal mask + online softmax (row stats shared across the
    // 16 tx-lanes of each row via shfl_xor; lanes of one tx-group are
    // contiguous within the 64-lane wave).
    const bool diag = (kt == qt);
#pragma unroll
    for (int i = 0; i < 4; ++i) {
      const int gq = qt * 64 + ty * 4 + i;
#pragma unroll
      for (int j = 0; j < 4; ++j) {
        float v = s[i][j] * scale;
        if (diag) {
          const int gk = kt * 64 + tx * 4 + j;
          if (gk > gq) v = -INFINITY;
        }
        s[i][j] = v;
      }
      float mm = fmaxf(fmaxf(s[i][0], s[i][1]), fmaxf(s[i][2], s[i][3]));
      mm = fmaxf(mm, __shfl_xor(mm, 1));
      mm = fmaxf(mm, __shfl_xor(mm, 2));
      mm = fmaxf(mm, __shfl_xor(mm, 4));
      mm = fmaxf(mm, __shfl_xor(mm, 8));
      const float mnew = fmaxf(m_run[i], mm);
      const float alpha = __expf(m_run[i] - mnew);  // exp(-inf)=0 on first tile
      float ps = 0.f;
#pragma unroll
      for (int j = 0; j < 4; ++j) {
        const float p = __expf(s[i][j] - mnew);     // masked -> exp(-inf)=0
        s[i][j] = p;
        ps += p;
      }
      ps += __shfl_xor(ps, 1);
      ps += __shfl_xor(ps, 2);
      ps += __shfl_xor(ps, 4);
      ps += __shfl_xor(ps, 8);
      l_run[i] = l_run[i] * alpha + ps;
      m_run[i] = mnew;
#pragma unroll
      for (int j = 0; j < 4; ++j) o[i][j] *= alpha;
      *reinterpret_cast<float4*>(&Ps[ty * 4 + i][tx * 4]) =
          make_float4(s[i][0], s[i][1], s[i][2], s[i][3]);
    }
    __syncthreads();

    // O += P . V   (P rows from LDS, V rows from LDS)
#pragma unroll
    for (int k4 = 0; k4 < 16; ++k4) {
      float4 pa[4];
#pragma unroll
      for (int i = 0; i < 4; ++i)
        pa[i] = *reinterpret_cast<const float4*>(&Ps[ty * 4 + i][k4 * 4]);
      float pr[4][4];
#pragma unroll
      for (int i = 0; i < 4; ++i) {
        pr[i][0] = pa[i].x; pr[i][1] = pa[i].y;
        pr[i][2] = pa[i].z; pr[i][3] = pa[i].w;
      }
#pragma unroll
      for (int c = 0; c < 4; ++c) {
        const float4 vb = *reinterpret_cast<const float4*>(&Vs[k4 * 4 + c][tx * 4]);
#pragma unroll
        for (int i = 0; i < 4; ++i) {
          o[i][0] = fmaf(pr[i][c], vb.x, o[i][0]);
          o[i][1] = fmaf(pr[i][c], vb.y, o[i][1]);
          o[i][2] = fmaf(pr[i][c], vb.z, o[i][2]);
          o[i][3] = fmaf(pr[i][c], vb.w, o[i][3]);
        }
      }
    }
    __syncthreads();
  }

  // epilogue: normalize and write Y in [B,T,C] layout
  const int b = bh / Hn, h = bh % Hn;
#pragma unroll
  for (int i = 0; i < 4; ++i) {
    const int t = qt * 64 + ty * 4 + i;
    const float inv = 1.f / l_run[i];
    float4 r;
    r.x = o[i][0] * inv;
    r.y = o[i][1] * inv;
    r.z = o[i][2] * inv;
    r.w = o[i][3] * inv;
    *reinterpret_cast<float4*>(
        &Y[((size_t)b * Tn + t) * Cn + h * Dn + tx * 4]) = r;
  }
}

// ---------------------------------------------------------------------------
extern "C" void kernel_launch(void* const* d_in, const int* in_sizes, int n_in,
                              void* d_out, int out_size, void* d_ws, size_t ws_size,
                              hipStream_t stream) {
  const float* x  = (const float*)d_in[0];
  const float* Wq = (const float*)d_in[1];
  const float* bq = (const float*)d_in[2];
  const float* Wk = (const float*)d_in[3];
  const float* bk = (const float*)d_in[4];
  const float* Wv = (const float*)d_in[5];
  const float* bv = (const float*)d_in[6];
  const float* Wp = (const float*)d_in[7];
  const float* bp = (const float*)d_in[8];
  float* out = (float*)d_out;

  // workspace layout: Q,K,V ([B,H,T,D] fp32) + Y ([B,T,C] fp32) = 128 MB
  const size_t elems = (size_t)Bsz * Hn * Tn * Dn;  // 8,388,608
  float* Qw = (float*)d_ws;
  float* Kw = Qw + elems;
  float* Vw = Kw + elems;
  float* Yw = Vw + elems;

  dim3 blk(256);
  dim3 ggrid(Cn / 64, (Bsz * Tn) / 64);  // (16, 128)

  gemm_bias_k<1><<<ggrid, blk, 0, stream>>>(x, Wq, bq, Qw);
  gemm_bias_k<1><<<ggrid, blk, 0, stream>>>(x, Wk, bk, Kw);
  gemm_bias_k<1><<<ggrid, blk, 0, stream>>>(x, Wv, bv, Vw);

  attn_k<<<dim3(Tn / 64, Bsz * Hn), blk, 0, stream>>>(Qw, Kw, Vw, Yw);

  gemm_bias_k<0><<<ggrid, blk, 0, stream>>>(Yw, Wp, bp, out);
}

// Round 2
// 404.452 us; speedup vs baseline: 6.0149x; 6.0149x over previous
//
#include <hip/hip_runtime.h>
#include <math.h>

// Problem constants
static constexpr int Bsz = 4;
static constexpr int Tn  = 2048;
static constexpr int Cn  = 1024;
static constexpr int Hn  = 16;
static constexpr int Dn  = 64;   // head dim

typedef __attribute__((ext_vector_type(8))) short bf16x8;
typedef __attribute__((ext_vector_type(4))) float f32x4;

#define MFMA16(a, b, c) __builtin_amdgcn_mfma_f32_16x16x32_bf16((a), (b), (c), 0, 0, 0)

__device__ __forceinline__ unsigned short f2bf(float f) {
  unsigned u = __float_as_uint(f);
  unsigned r = (u + 0x7fffu + ((u >> 16) & 1u)) >> 16;  // RNE
  return (unsigned short)r;
}

__device__ __forceinline__ void load_lds16(const void* g, void* l) {
  __builtin_amdgcn_global_load_lds(
      (const __attribute__((address_space(1))) void*)g,
      (__attribute__((address_space(3))) void*)l, 16, 0, 0);
}

// ---------------------------------------------------------------------------
// Prep 1: x fp32 -> bf16 (8 elems/thread)
// ---------------------------------------------------------------------------
__global__ __launch_bounds__(256) void convert_x_k(
    const float* __restrict__ x, unsigned short* __restrict__ xb) {
  const int i = blockIdx.x * blockDim.x + threadIdx.x;  // 8 elems each
  const float4 a = ((const float4*)x)[i * 2 + 0];
  const float4 b = ((const float4*)x)[i * 2 + 1];
  uint4 o;
  o.x = (unsigned)f2bf(a.x) | ((unsigned)f2bf(a.y) << 16);
  o.y = (unsigned)f2bf(a.z) | ((unsigned)f2bf(a.w) << 16);
  o.z = (unsigned)f2bf(b.x) | ((unsigned)f2bf(b.y) << 16);
  o.w = (unsigned)f2bf(b.z) | ((unsigned)f2bf(b.w) << 16);
  ((uint4*)xb)[i] = o;
}

// ---------------------------------------------------------------------------
// Prep 2: W [K][N] fp32 -> Wt [N][K] bf16, 4 weights via blockIdx.z
// ---------------------------------------------------------------------------
__global__ __launch_bounds__(256) void transpose_w_k(
    const float* __restrict__ w0, const float* __restrict__ w1,
    const float* __restrict__ w2, const float* __restrict__ w3,
    unsigned short* __restrict__ o0, unsigned short* __restrict__ o1,
    unsigned short* __restrict__ o2, unsigned short* __restrict__ o3) {
  __shared__ unsigned short Ts[64][65];
  const float* W;
  unsigned short* O;
  switch (blockIdx.z) {
    case 0: W = w0; O = o0; break;
    case 1: W = w1; O = o1; break;
    case 2: W = w2; O = o2; break;
    default: W = w3; O = o3; break;
  }
  const int k0 = blockIdx.y * 64, n0 = blockIdx.x * 64;
  const int tid = threadIdx.x;
  const int cr = tid >> 4, cc = (tid & 15) * 4;
#pragma unroll
  for (int p = 0; p < 4; ++p) {
    const int r = p * 16 + cr;
    const float4 v = *(const float4*)&W[(size_t)(k0 + r) * Cn + n0 + cc];
    Ts[r][cc + 0] = f2bf(v.x);
    Ts[r][cc + 1] = f2bf(v.y);
    Ts[r][cc + 2] = f2bf(v.z);
    Ts[r][cc + 3] = f2bf(v.w);
  }
  __syncthreads();
#pragma unroll
  for (int p = 0; p < 4; ++p) {
    const int n = p * 16 + cr;
    ushort4 o;
    o.x = Ts[cc + 0][n];
    o.y = Ts[cc + 1][n];
    o.z = Ts[cc + 2][n];
    o.w = Ts[cc + 3][n];
    *(ushort4*)&O[(size_t)(n0 + n) * Cn + k0 + cc] = o;
  }
}

// ---------------------------------------------------------------------------
// MFMA GEMM: out = A[M,1024] @ Wt^T + bias, A and Wt both bf16, K-contiguous.
// Tile 128x128, BK=64, 4 waves (2x2), each wave 4x4 tiles of 16x16x32.
// OUT_MODE 0: fp32 out[m*1024+n]
// OUT_MODE 1: bf16 heads [B,H,T,D]
// OUT_MODE 2: bf16 V^T   [B,H,D,T]
// ---------------------------------------------------------------------------
template<int OUT_MODE>
__global__ __launch_bounds__(256, 2) void gemm_mfma_k(
    const unsigned short* __restrict__ A, const unsigned short* __restrict__ Bt,
    const float* __restrict__ bias, void* __restrict__ outv) {
  __shared__ unsigned short As[128 * 64];
  __shared__ unsigned short Bs[128 * 64];
  const int tid = threadIdx.x;
  const int lane = tid & 63, w = tid >> 6;
  const int wm = w >> 1, wn = w & 1;
  const int row0 = blockIdx.y * 128, col0 = blockIdx.x * 128;
  const int lr = lane & 15, lg = lane >> 4;

  const f32x4 fz = {0.f, 0.f, 0.f, 0.f};
  f32x4 acc[4][4];
#pragma unroll
  for (int i = 0; i < 4; ++i)
#pragma unroll
    for (int j = 0; j < 4; ++j) acc[i][j] = fz;

  for (int k0 = 0; k0 < Cn; k0 += 64) {
#pragma unroll
    for (int it = 0; it < 4; ++it) {
      const int c = it * 256 + tid;
      const int r = c >> 3, ko = (c & 7) << 3;
      load_lds16(A + (size_t)(row0 + r) * Cn + k0 + ko, &As[c * 8]);
    }
#pragma unroll
    for (int it = 0; it < 4; ++it) {
      const int c = it * 256 + tid;
      const int r = c >> 3, ko = (c & 7) << 3;
      load_lds16(Bt + (size_t)(col0 + r) * Cn + k0 + ko, &Bs[c * 8]);
    }
    __syncthreads();
#pragma unroll
    for (int ks = 0; ks < 2; ++ks) {
      bf16x8 af[4], bfr[4];
#pragma unroll
      for (int mi = 0; mi < 4; ++mi)
        af[mi] = *(const bf16x8*)&As[(wm * 64 + mi * 16 + lr) * 64 + ks * 32 + lg * 8];
#pragma unroll
      for (int ni = 0; ni < 4; ++ni)
        bfr[ni] = *(const bf16x8*)&Bs[(wn * 64 + ni * 16 + lr) * 64 + ks * 32 + lg * 8];
#pragma unroll
      for (int mi = 0; mi < 4; ++mi)
#pragma unroll
        for (int ni = 0; ni < 4; ++ni)
          acc[mi][ni] = MFMA16(af[mi], bfr[ni], acc[mi][ni]);
    }
    __syncthreads();
  }

  // epilogue: C/D layout col = lane&15, row = (lane>>4)*4 + reg
#pragma unroll
  for (int mi = 0; mi < 4; ++mi) {
#pragma unroll
    for (int ni = 0; ni < 4; ++ni) {
      const int col = col0 + wn * 64 + ni * 16 + lr;
      const float bv = bias[col];
#pragma unroll
      for (int r = 0; r < 4; ++r) {
        const int row = row0 + wm * 64 + mi * 16 + lg * 4 + r;
        const float val = acc[mi][ni][r] + bv;
        if (OUT_MODE == 0) {
          ((float*)outv)[(size_t)row * Cn + col] = val;
        } else if (OUT_MODE == 1) {
          const int b = row >> 11, t = row & (Tn - 1);
          const int h = col >> 6, d = col & 63;
          ((unsigned short*)outv)[((((size_t)b * Hn + h) * Tn + t) << 6) + d] = f2bf(val);
        } else {
          const int b = row >> 11, t = row & (Tn - 1);
          const int h = col >> 6, d = col & 63;
          ((unsigned short*)outv)[(((size_t)b * Hn + h) * Dn + d) * Tn + t] = f2bf(val);
        }
      }
    }
  }
}

// ---------------------------------------------------------------------------
// Flash attention, bf16 MFMA. Q,K: [B,H,T,D]; Vt: [B,H,D,T]; Y: [B,T,C] bf16.
// Grid (32, 64). 4 waves; wave w owns q-rows [w*16, w*16+16) of the 64-q tile.
// ---------------------------------------------------------------------------
__global__ __launch_bounds__(256, 2) void attn_mfma_k(
    const unsigned short* __restrict__ Q, const unsigned short* __restrict__ K,
    const unsigned short* __restrict__ Vt, unsigned short* __restrict__ Y) {
  __shared__ unsigned short Ks[64 * 64];
  __shared__ unsigned short Vs[64 * 64];   // V^T tile: [d][key]
  __shared__ unsigned short Ps[4][16 * 64];
  const int tid = threadIdx.x, lane = tid & 63, w = tid >> 6;
  const int lr = lane & 15, lg = lane >> 4;
  const int qt = blockIdx.x, bh = blockIdx.y;
  const size_t base = (size_t)bh * Tn * Dn;

  // Q fragments (A operand): row = lane&15, k = (lane>>4)*8 + j
  bf16x8 qf[2];
  {
    const int qrow = qt * 64 + w * 16 + lr;
#pragma unroll
    for (int ks = 0; ks < 2; ++ks)
      qf[ks] = *(const bf16x8*)&Q[base + (size_t)qrow * Dn + ks * 32 + lg * 8];
  }

  const f32x4 fz = {0.f, 0.f, 0.f, 0.f};
  f32x4 oacc[4];
#pragma unroll
  for (int i = 0; i < 4; ++i) oacc[i] = fz;
  float m_run[4], l_run[4];
#pragma unroll
  for (int i = 0; i < 4; ++i) { m_run[i] = -1e30f; l_run[i] = 0.f; }

  for (int kt = 0; kt <= qt; ++kt) {
    // stage K tile [key][d] and V^T tile [d][key]
#pragma unroll
    for (int it = 0; it < 2; ++it) {
      const int c = it * 256 + tid;
      const int r = c >> 3, o = (c & 7) << 3;
      load_lds16(K + base + (size_t)(kt * 64 + r) * Dn + o, &Ks[c * 8]);
    }
#pragma unroll
    for (int it = 0; it < 2; ++it) {
      const int c = it * 256 + tid;
      const int r = c >> 3, o = (c & 7) << 3;  // r = d, o = t offset
      load_lds16(Vt + base + (size_t)r * Tn + kt * 64 + o, &Vs[c * 8]);
    }
    __syncthreads();

    // S = Q . K^T  (4 n-tiles of 16 keys, K-dim = D = 64)
    f32x4 s[4];
#pragma unroll
    for (int ni = 0; ni < 4; ++ni) s[ni] = fz;
#pragma unroll
    for (int ni = 0; ni < 4; ++ni)
#pragma unroll
      for (int ks = 0; ks < 2; ++ks) {
        const bf16x8 kf = *(const bf16x8*)&Ks[(ni * 16 + lr) * 64 + ks * 32 + lg * 8];
        s[ni] = MFMA16(qf[ks], kf, s[ni]);
      }

    // online softmax; row r of S lives at reg r&3, lanes (r>>2)*16..+15
    const bool diag = (kt == qt);
#pragma unroll
    for (int i = 0; i < 4; ++i) {
      const int gq = qt * 64 + w * 16 + lg * 4 + i;
      float sv[4];
#pragma unroll
      for (int ni = 0; ni < 4; ++ni) {
        float v = s[ni][i] * 0.125f;
        if (diag) {
          const int gk = kt * 64 + ni * 16 + lr;
          if (gk > gq) v = -1e30f;
        }
        sv[ni] = v;
      }
      float mm = fmaxf(fmaxf(sv[0], sv[1]), fmaxf(sv[2], sv[3]));
      mm = fmaxf(mm, __shfl_xor(mm, 1));
      mm = fmaxf(mm, __shfl_xor(mm, 2));
      mm = fmaxf(mm, __shfl_xor(mm, 4));
      mm = fmaxf(mm, __shfl_xor(mm, 8));
      const float mnew = fmaxf(m_run[i], mm);
      const float alpha = __expf(m_run[i] - mnew);
      float ps = 0.f;
#pragma unroll
      for (int ni = 0; ni < 4; ++ni) {
        const float p = __expf(sv[ni] - mnew);
        ps += p;
        Ps[w][(lg * 4 + i) * 64 + ni * 16 + lr] = f2bf(p);
      }
      ps += __shfl_xor(ps, 1);
      ps += __shfl_xor(ps, 2);
      ps += __shfl_xor(ps, 4);
      ps += __shfl_xor(ps, 8);
      l_run[i] = l_run[i] * alpha + ps;
      m_run[i] = mnew;
#pragma unroll
      for (int nd = 0; nd < 4; ++nd) oacc[nd][i] *= alpha;
    }

    // O += P . V : A = P (rows=q, k=key), B = V^T tile (k=key, col=d)
#pragma unroll
    for (int ks = 0; ks < 2; ++ks) {
      const bf16x8 pa = *(const bf16x8*)&Ps[w][lr * 64 + ks * 32 + lg * 8];
#pragma unroll
      for (int nd = 0; nd < 4; ++nd) {
        const bf16x8 vf = *(const bf16x8*)&Vs[(nd * 16 + lr) * 64 + ks * 32 + lg * 8];
        oacc[nd] = MFMA16(pa, vf, oacc[nd]);
      }
    }
    __syncthreads();
  }

  // epilogue -> Y [B,T,C] bf16
  const int b = bh >> 4, h = bh & 15;
#pragma unroll
  for (int i = 0; i < 4; ++i) {
    const int t = qt * 64 + w * 16 + lg * 4 + i;
    const float inv = 1.f / l_run[i];
#pragma unroll
    for (int nd = 0; nd < 4; ++nd) {
      const int d = nd * 16 + lr;
      Y[((size_t)b * Tn + t) * Cn + h * Dn + d] = f2bf(oacc[nd][i] * inv);
    }
  }
}

// ---------------------------------------------------------------------------
extern "C" void kernel_launch(void* const* d_in, const int* in_sizes, int n_in,
                              void* d_out, int out_size, void* d_ws, size_t ws_size,
                              hipStream_t stream) {
  const float* x  = (const float*)d_in[0];
  const float* Wq = (const float*)d_in[1];
  const float* bq = (const float*)d_in[2];
  const float* Wk = (const float*)d_in[3];
  const float* bk = (const float*)d_in[4];
  const float* Wv = (const float*)d_in[5];
  const float* bv = (const float*)d_in[6];
  const float* Wp = (const float*)d_in[7];
  const float* bp = (const float*)d_in[8];
  float* out = (float*)d_out;

  const size_t xe = (size_t)Bsz * Tn * Cn;  // 8,388,608
  const size_t we = (size_t)Cn * Cn;        // 1,048,576
  unsigned short* p = (unsigned short*)d_ws;
  unsigned short* xb  = p; p += xe;
  unsigned short* Wqt = p; p += we;
  unsigned short* Wkt = p; p += we;
  unsigned short* Wvt = p; p += we;
  unsigned short* Wpt = p; p += we;
  unsigned short* Qb  = p; p += xe;
  unsigned short* Kb  = p; p += xe;
  unsigned short* Vtb = p; p += xe;
  unsigned short* Yb  = p; p += xe;

  convert_x_k<<<dim3((int)(xe / 8 / 256)), dim3(256), 0, stream>>>(x, xb);
  transpose_w_k<<<dim3(16, 16, 4), dim3(256), 0, stream>>>(
      Wq, Wk, Wv, Wp, Wqt, Wkt, Wvt, Wpt);

  const dim3 ggrid(Cn / 128, (Bsz * Tn) / 128);  // (8, 64)
  gemm_mfma_k<1><<<ggrid, dim3(256), 0, stream>>>(xb, Wqt, bq, Qb);
  gemm_mfma_k<1><<<ggrid, dim3(256), 0, stream>>>(xb, Wkt, bk, Kb);
  gemm_mfma_k<2><<<ggrid, dim3(256), 0, stream>>>(xb, Wvt, bv, Vtb);

  attn_mfma_k<<<dim3(Tn / 64, Bsz * Hn), dim3(256), 0, stream>>>(Qb, Kb, Vtb, Yb);

  gemm_mfma_k<0><<<ggrid, dim3(256), 0, stream>>>(Yb, Wpt, bp, out);
}

// Round 3
// 337.395 us; speedup vs baseline: 7.2104x; 1.1987x over previous
//
#include <hip/hip_runtime.h>
#include <math.h>

// Problem constants
static constexpr int Bsz = 4;
static constexpr int Tn  = 2048;
static constexpr int Cn  = 1024;
static constexpr int Hn  = 16;
static constexpr int Dn  = 64;   // head dim

typedef __attribute__((ext_vector_type(8))) short bf16x8;
typedef __attribute__((ext_vector_type(4))) float f32x4;

#define MFMA16(a, b, c) __builtin_amdgcn_mfma_f32_16x16x32_bf16((a), (b), (c), 0, 0, 0)

__device__ __forceinline__ unsigned short f2bf(float f) {
  unsigned u = __float_as_uint(f);
  unsigned r = (u + 0x7fffu + ((u >> 16) & 1u)) >> 16;  // RNE
  return (unsigned short)r;
}

__device__ __forceinline__ void load_lds16(const void* g, void* l) {
  __builtin_amdgcn_global_load_lds(
      (const __attribute__((address_space(1))) void*)g,
      (__attribute__((address_space(3))) void*)l, 16, 0, 0);
}

// ---------------------------------------------------------------------------
// Prep 1: x fp32 -> bf16 (8 elems/thread)
// ---------------------------------------------------------------------------
__global__ __launch_bounds__(256) void convert_x_k(
    const float* __restrict__ x, unsigned short* __restrict__ xb) {
  const int i = blockIdx.x * blockDim.x + threadIdx.x;  // 8 elems each
  const float4 a = ((const float4*)x)[i * 2 + 0];
  const float4 b = ((const float4*)x)[i * 2 + 1];
  uint4 o;
  o.x = (unsigned)f2bf(a.x) | ((unsigned)f2bf(a.y) << 16);
  o.y = (unsigned)f2bf(a.z) | ((unsigned)f2bf(a.w) << 16);
  o.z = (unsigned)f2bf(b.x) | ((unsigned)f2bf(b.y) << 16);
  o.w = (unsigned)f2bf(b.z) | ((unsigned)f2bf(b.w) << 16);
  ((uint4*)xb)[i] = o;
}

// ---------------------------------------------------------------------------
// Prep 2: W [K][N] fp32 -> Wt [N][K] bf16, 4 weights via blockIdx.z
// ---------------------------------------------------------------------------
__global__ __launch_bounds__(256) void transpose_w_k(
    const float* __restrict__ w0, const float* __restrict__ w1,
    const float* __restrict__ w2, const float* __restrict__ w3,
    unsigned short* __restrict__ o0, unsigned short* __restrict__ o1,
    unsigned short* __restrict__ o2, unsigned short* __restrict__ o3) {
  __shared__ unsigned short Ts[64][65];
  const float* W;
  unsigned short* O;
  switch (blockIdx.z) {
    case 0: W = w0; O = o0; break;
    case 1: W = w1; O = o1; break;
    case 2: W = w2; O = o2; break;
    default: W = w3; O = o3; break;
  }
  const int k0 = blockIdx.y * 64, n0 = blockIdx.x * 64;
  const int tid = threadIdx.x;
  const int cr = tid >> 4, cc = (tid & 15) * 4;
#pragma unroll
  for (int p = 0; p < 4; ++p) {
    const int r = p * 16 + cr;
    const float4 v = *(const float4*)&W[(size_t)(k0 + r) * Cn + n0 + cc];
    Ts[r][cc + 0] = f2bf(v.x);
    Ts[r][cc + 1] = f2bf(v.y);
    Ts[r][cc + 2] = f2bf(v.z);
    Ts[r][cc + 3] = f2bf(v.w);
  }
  __syncthreads();
#pragma unroll
  for (int p = 0; p < 4; ++p) {
    const int n = p * 16 + cr;
    ushort4 o;
    o.x = Ts[cc + 0][n];
    o.y = Ts[cc + 1][n];
    o.z = Ts[cc + 2][n];
    o.w = Ts[cc + 3][n];
    *(ushort4*)&O[(size_t)(n0 + n) * Cn + k0 + cc] = o;
  }
}

// ---------------------------------------------------------------------------
// MFMA GEMM: out = A[M,1024] @ Wt^T + bias, A and Wt both bf16, K-contiguous.
// Tile 128x128, BK=64, 4 waves (2x2), each wave 4x4 tiles of 16x16x32.
// OUT_MODE 0: fp32 out[m*1024+n]
// OUT_MODE 1: bf16 heads [B,H,T,D]
// OUT_MODE 2: bf16 V^T   [B,H,D,T]
// ---------------------------------------------------------------------------
template<int OUT_MODE>
__global__ __launch_bounds__(256, 2) void gemm_mfma_k(
    const unsigned short* __restrict__ A, const unsigned short* __restrict__ Bt,
    const float* __restrict__ bias, void* __restrict__ outv) {
  __shared__ unsigned short As[128 * 64];
  __shared__ unsigned short Bs[128 * 64];
  const int tid = threadIdx.x;
  const int lane = tid & 63, w = tid >> 6;
  const int wm = w >> 1, wn = w & 1;
  const int row0 = blockIdx.y * 128, col0 = blockIdx.x * 128;
  const int lr = lane & 15, lg = lane >> 4;

  const f32x4 fz = {0.f, 0.f, 0.f, 0.f};
  f32x4 acc[4][4];
#pragma unroll
  for (int i = 0; i < 4; ++i)
#pragma unroll
    for (int j = 0; j < 4; ++j) acc[i][j] = fz;

  for (int k0 = 0; k0 < Cn; k0 += 64) {
#pragma unroll
    for (int it = 0; it < 4; ++it) {
      const int c = it * 256 + tid;
      const int r = c >> 3, ko = (c & 7) << 3;
      load_lds16(A + (size_t)(row0 + r) * Cn + k0 + ko, &As[c * 8]);
    }
#pragma unroll
    for (int it = 0; it < 4; ++it) {
      const int c = it * 256 + tid;
      const int r = c >> 3, ko = (c & 7) << 3;
      load_lds16(Bt + (size_t)(col0 + r) * Cn + k0 + ko, &Bs[c * 8]);
    }
    __syncthreads();
#pragma unroll
    for (int ks = 0; ks < 2; ++ks) {
      bf16x8 af[4], bfr[4];
#pragma unroll
      for (int mi = 0; mi < 4; ++mi)
        af[mi] = *(const bf16x8*)&As[(wm * 64 + mi * 16 + lr) * 64 + ks * 32 + lg * 8];
#pragma unroll
      for (int ni = 0; ni < 4; ++ni)
        bfr[ni] = *(const bf16x8*)&Bs[(wn * 64 + ni * 16 + lr) * 64 + ks * 32 + lg * 8];
#pragma unroll
      for (int mi = 0; mi < 4; ++mi)
#pragma unroll
        for (int ni = 0; ni < 4; ++ni)
          acc[mi][ni] = MFMA16(af[mi], bfr[ni], acc[mi][ni]);
    }
    __syncthreads();
  }

  // epilogue: C/D layout col = lane&15, row = (lane>>4)*4 + reg
#pragma unroll
  for (int mi = 0; mi < 4; ++mi) {
#pragma unroll
    for (int ni = 0; ni < 4; ++ni) {
      const int col = col0 + wn * 64 + ni * 16 + lr;
      const float bv = bias[col];
#pragma unroll
      for (int r = 0; r < 4; ++r) {
        const int row = row0 + wm * 64 + mi * 16 + lg * 4 + r;
        const float val = acc[mi][ni][r] + bv;
        if (OUT_MODE == 0) {
          ((float*)outv)[(size_t)row * Cn + col] = val;
        } else if (OUT_MODE == 1) {
          const int b = row >> 11, t = row & (Tn - 1);
          const int h = col >> 6, d = col & 63;
          ((unsigned short*)outv)[((((size_t)b * Hn + h) * Tn + t) << 6) + d] = f2bf(val);
        } else {
          const int b = row >> 11, t = row & (Tn - 1);
          const int h = col >> 6, d = col & 63;
          ((unsigned short*)outv)[(((size_t)b * Hn + h) * Dn + d) * Tn + t] = f2bf(val);
        }
      }
    }
  }
}

// ---------------------------------------------------------------------------
// Flash attention, bf16 MFMA, XOR-swizzled LDS + double-buffered K/V.
// Q,K: [B,H,T,D]; Vt: [B,H,D,T]; Y: [B,T,C] bf16.
// Grid (32, 64), qt reversed (LPT). 4 waves; wave w owns q-rows w*16..w*16+15.
//
// Swizzle scheme (rule #21: linear LDS dest for global_load_lds, inverse-
// swizzled GLOBAL source, swizzled read): tiles are [64 rows][8 chunks of
// 16B]; physical chunk p of row r holds logical chunk p ^ (r&7).
// ---------------------------------------------------------------------------
__global__ __launch_bounds__(256, 2) void attn_mfma_k(
    const unsigned short* __restrict__ Q, const unsigned short* __restrict__ K,
    const unsigned short* __restrict__ Vt, unsigned short* __restrict__ Y) {
  __shared__ unsigned short Ks[2][64 * 64];
  __shared__ unsigned short Vs[2][64 * 64];   // V^T tile: [d][key]
  __shared__ unsigned short Ps[4][16 * 64];
  const int tid = threadIdx.x, lane = tid & 63, w = tid >> 6;
  const int lr = lane & 15, lg = lane >> 4;
  const int qt = (int)gridDim.x - 1 - blockIdx.x;  // heavy blocks first
  const int bh = blockIdx.y;
  const size_t base = (size_t)bh * Tn * Dn;
  const float kSc = 0.18033688f;  // 0.125 * log2(e)

  // Q fragments (A operand): row = lane&15, k = (lane>>4)*8 + j
  bf16x8 qf[2];
  {
    const int qrow = qt * 64 + w * 16 + lr;
#pragma unroll
    for (int ks = 0; ks < 2; ++ks)
      qf[ks] = *(const bf16x8*)&Q[base + (size_t)qrow * Dn + ks * 32 + lg * 8];
  }

  // stage K tile [key][d] and V^T tile [d][key] with pre-swizzled source
  auto stage = [&](int buf, int kt) {
#pragma unroll
    for (int it = 0; it < 2; ++it) {
      const int c = it * 256 + tid;
      const int r = c >> 3;
      const int lc = (c & 7) ^ (r & 7);  // logical chunk for this physical slot
      load_lds16(K + base + (size_t)(kt * 64 + r) * Dn + lc * 8, &Ks[buf][c * 8]);
      load_lds16(Vt + base + (size_t)r * Tn + kt * 64 + lc * 8, &Vs[buf][c * 8]);
    }
  };

  const f32x4 fz = {0.f, 0.f, 0.f, 0.f};
  f32x4 oacc[4];
#pragma unroll
  for (int i = 0; i < 4; ++i) oacc[i] = fz;
  float m_run[4], l_run[4];
#pragma unroll
  for (int i = 0; i < 4; ++i) { m_run[i] = -1e30f; l_run[i] = 0.f; }

  stage(0, 0);
  asm volatile("s_waitcnt vmcnt(0)" ::: "memory");
  __syncthreads();
  int cur = 0;

  for (int kt = 0; kt <= qt; ++kt) {
    if (kt < qt) stage(cur ^ 1, kt + 1);  // prefetch next tile (other buffer)

    // S = Q . K^T  (4 n-tiles of 16 keys, K-dim = D = 64)
    f32x4 s[4];
#pragma unroll
    for (int ni = 0; ni < 4; ++ni) s[ni] = fz;
#pragma unroll
    for (int ni = 0; ni < 4; ++ni)
#pragma unroll
      for (int ks = 0; ks < 2; ++ks) {
        const bf16x8 kf = *(const bf16x8*)
            &Ks[cur][(ni * 16 + lr) * 64 + (((ks * 4 + lg) ^ (lr & 7)) << 3)];
        s[ni] = MFMA16(qf[ks], kf, s[ni]);
      }

    // online softmax (scaled-by-log2e domain, exp2); row r of S: reg r&3,
    // lane group r>>2
    const bool diag = (kt == qt);
#pragma unroll
    for (int i = 0; i < 4; ++i) {
      const int gq = qt * 64 + w * 16 + lg * 4 + i;
      const int prow = lg * 4 + i;
      float sv[4];
#pragma unroll
      for (int ni = 0; ni < 4; ++ni) {
        float v = s[ni][i] * kSc;
        if (diag) {
          const int gk = kt * 64 + ni * 16 + lr;
          if (gk > gq) v = -1e30f;
        }
        sv[ni] = v;
      }
      float mm = fmaxf(fmaxf(sv[0], sv[1]), fmaxf(sv[2], sv[3]));
      mm = fmaxf(mm, __shfl_xor(mm, 1));
      mm = fmaxf(mm, __shfl_xor(mm, 2));
      mm = fmaxf(mm, __shfl_xor(mm, 4));
      mm = fmaxf(mm, __shfl_xor(mm, 8));
      const float mnew = fmaxf(m_run[i], mm);
      const float alpha = exp2f(m_run[i] - mnew);
      float ps = 0.f;
#pragma unroll
      for (int ni = 0; ni < 4; ++ni) {
        const float p = exp2f(sv[ni] - mnew);
        ps += p;
        Ps[w][prow * 64 + ((((ni * 2) + (lr >> 3)) ^ (prow & 7)) << 3) + (lr & 7)] =
            f2bf(p);
      }
      ps += __shfl_xor(ps, 1);
      ps += __shfl_xor(ps, 2);
      ps += __shfl_xor(ps, 4);
      ps += __shfl_xor(ps, 8);
      l_run[i] = l_run[i] * alpha + ps;
      m_run[i] = mnew;
#pragma unroll
      for (int nd = 0; nd < 4; ++nd) oacc[nd][i] *= alpha;
    }

    // O += P . V : A = P (rows=q, k=key), B = V^T tile (rows=d, k=key)
#pragma unroll
    for (int ks = 0; ks < 2; ++ks) {
      const bf16x8 pa = *(const bf16x8*)
          &Ps[w][lr * 64 + (((ks * 4 + lg) ^ (lr & 7)) << 3)];
#pragma unroll
      for (int nd = 0; nd < 4; ++nd) {
        const bf16x8 vf = *(const bf16x8*)
            &Vs[cur][(nd * 16 + lr) * 64 + (((ks * 4 + lg) ^ (lr & 7)) << 3)];
        oacc[nd] = MFMA16(pa, vf, oacc[nd]);
      }
    }

    asm volatile("s_waitcnt vmcnt(0)" ::: "memory");  // prefetch landed
    __syncthreads();
    cur ^= 1;
  }

  // epilogue -> Y [B,T,C] bf16
  const int b = bh >> 4, h = bh & 15;
#pragma unroll
  for (int i = 0; i < 4; ++i) {
    const int t = qt * 64 + w * 16 + lg * 4 + i;
    const float inv = 1.f / l_run[i];
#pragma unroll
    for (int nd = 0; nd < 4; ++nd) {
      const int d = nd * 16 + lr;
      Y[((size_t)b * Tn + t) * Cn + h * Dn + d] = f2bf(oacc[nd][i] * inv);
    }
  }
}

// ---------------------------------------------------------------------------
extern "C" void kernel_launch(void* const* d_in, const int* in_sizes, int n_in,
                              void* d_out, int out_size, void* d_ws, size_t ws_size,
                              hipStream_t stream) {
  const float* x  = (const float*)d_in[0];
  const float* Wq = (const float*)d_in[1];
  const float* bq = (const float*)d_in[2];
  const float* Wk = (const float*)d_in[3];
  const float* bk = (const float*)d_in[4];
  const float* Wv = (const float*)d_in[5];
  const float* bv = (const float*)d_in[6];
  const float* Wp = (const float*)d_in[7];
  const float* bp = (const float*)d_in[8];
  float* out = (float*)d_out;

  const size_t xe = (size_t)Bsz * Tn * Cn;  // 8,388,608
  const size_t we = (size_t)Cn * Cn;        // 1,048,576
  unsigned short* p = (unsigned short*)d_ws;
  unsigned short* xb  = p; p += xe;
  unsigned short* Wqt = p; p += we;
  unsigned short* Wkt = p; p += we;
  unsigned short* Wvt = p; p += we;
  unsigned short* Wpt = p; p += we;
  unsigned short* Qb  = p; p += xe;
  unsigned short* Kb  = p; p += xe;
  unsigned short* Vtb = p; p += xe;
  unsigned short* Yb  = p; p += xe;

  convert_x_k<<<dim3((int)(xe / 8 / 256)), dim3(256), 0, stream>>>(x, xb);
  transpose_w_k<<<dim3(16, 16, 4), dim3(256), 0, stream>>>(
      Wq, Wk, Wv, Wp, Wqt, Wkt, Wvt, Wpt);

  const dim3 ggrid(Cn / 128, (Bsz * Tn) / 128);  // (8, 64)
  gemm_mfma_k<1><<<ggrid, dim3(256), 0, stream>>>(xb, Wqt, bq, Qb);
  gemm_mfma_k<1><<<ggrid, dim3(256), 0, stream>>>(xb, Wkt, bk, Kb);
  gemm_mfma_k<2><<<ggrid, dim3(256), 0, stream>>>(xb, Wvt, bv, Vtb);

  attn_mfma_k<<<dim3(Tn / 64, Bsz * Hn), dim3(256), 0, stream>>>(Qb, Kb, Vtb, Yb);

  gemm_mfma_k<0><<<ggrid, dim3(256), 0, stream>>>(Yb, Wpt, bp, out);
}

// Round 4
// 277.035 us; speedup vs baseline: 8.7814x; 1.2179x over previous
//
#include <hip/hip_runtime.h>
#include <math.h>

// Problem constants
static constexpr int Bsz = 4;
static constexpr int Tn  = 2048;
static constexpr int Cn  = 1024;
static constexpr int Hn  = 16;
static constexpr int Dn  = 64;   // head dim

typedef __attribute__((ext_vector_type(8))) short bf16x8;
typedef __attribute__((ext_vector_type(4))) float f32x4;

#define MFMA16(a, b, c) __builtin_amdgcn_mfma_f32_16x16x32_bf16((a), (b), (c), 0, 0, 0)

static constexpr float kQScale = 0.18033688f;  // 0.125 * log2(e)

__device__ __forceinline__ unsigned short f2bf(float f) {
  unsigned u = __float_as_uint(f);
  unsigned r = (u + 0x7fffu + ((u >> 16) & 1u)) >> 16;  // RNE
  return (unsigned short)r;
}

__device__ __forceinline__ unsigned cvtpk_bf16(float lo, float hi) {
  unsigned r;
  asm("v_cvt_pk_bf16_f32 %0, %1, %2" : "=v"(r) : "v"(lo), "v"(hi));
  return r;
}

__device__ __forceinline__ void load_lds16(const void* g, void* l) {
  __builtin_amdgcn_global_load_lds(
      (const __attribute__((address_space(1))) void*)g,
      (__attribute__((address_space(3))) void*)l, 16, 0, 0);
}

// ---------------------------------------------------------------------------
// Prep 1: x fp32 -> bf16 (8 elems/thread)
// ---------------------------------------------------------------------------
__global__ __launch_bounds__(256) void convert_x_k(
    const float* __restrict__ x, unsigned short* __restrict__ xb) {
  const int i = blockIdx.x * blockDim.x + threadIdx.x;  // 8 elems each
  const float4 a = ((const float4*)x)[i * 2 + 0];
  const float4 b = ((const float4*)x)[i * 2 + 1];
  uint4 o;
  o.x = cvtpk_bf16(a.x, a.y);
  o.y = cvtpk_bf16(a.z, a.w);
  o.z = cvtpk_bf16(b.x, b.y);
  o.w = cvtpk_bf16(b.z, b.w);
  ((uint4*)xb)[i] = o;
}

// ---------------------------------------------------------------------------
// Prep 2: W [K][N] fp32 -> Wt [N][K] bf16, 4 weights via blockIdx.z
// ---------------------------------------------------------------------------
__global__ __launch_bounds__(256) void transpose_w_k(
    const float* __restrict__ w0, const float* __restrict__ w1,
    const float* __restrict__ w2, const float* __restrict__ w3,
    unsigned short* __restrict__ o0, unsigned short* __restrict__ o1,
    unsigned short* __restrict__ o2, unsigned short* __restrict__ o3) {
  __shared__ unsigned short Ts[64][65];
  const float* W;
  unsigned short* O;
  switch (blockIdx.z) {
    case 0: W = w0; O = o0; break;
    case 1: W = w1; O = o1; break;
    case 2: W = w2; O = o2; break;
    default: W = w3; O = o3; break;
  }
  const int k0 = blockIdx.y * 64, n0 = blockIdx.x * 64;
  const int tid = threadIdx.x;
  const int cr = tid >> 4, cc = (tid & 15) * 4;
#pragma unroll
  for (int p = 0; p < 4; ++p) {
    const int r = p * 16 + cr;
    const float4 v = *(const float4*)&W[(size_t)(k0 + r) * Cn + n0 + cc];
    Ts[r][cc + 0] = f2bf(v.x);
    Ts[r][cc + 1] = f2bf(v.y);
    Ts[r][cc + 2] = f2bf(v.z);
    Ts[r][cc + 3] = f2bf(v.w);
  }
  __syncthreads();
#pragma unroll
  for (int p = 0; p < 4; ++p) {
    const int n = p * 16 + cr;
    ushort4 o;
    o.x = Ts[cc + 0][n];
    o.y = Ts[cc + 1][n];
    o.z = Ts[cc + 2][n];
    o.w = Ts[cc + 3][n];
    *(ushort4*)&O[(size_t)(n0 + n) * Cn + k0 + cc] = o;
  }
}

// ---------------------------------------------------------------------------
// Shared GEMM main loop: acc = A[128 rows] @ Bt[128 rows]^T over K=1024.
// ---------------------------------------------------------------------------
__device__ __forceinline__ void gemm_core(
    const unsigned short* __restrict__ A, const unsigned short* __restrict__ Bt,
    int row0, int col0, unsigned short* As, unsigned short* Bs,
    f32x4 acc[4][4]) {
  const int tid = threadIdx.x;
  const int lane = tid & 63, w = tid >> 6;
  const int wm = w >> 1, wn = w & 1;
  const int lr = lane & 15, lg = lane >> 4;

  for (int k0 = 0; k0 < Cn; k0 += 64) {
#pragma unroll
    for (int it = 0; it < 4; ++it) {
      const int c = it * 256 + tid;
      const int r = c >> 3, ko = (c & 7) << 3;
      load_lds16(A + (size_t)(row0 + r) * Cn + k0 + ko, &As[c * 8]);
    }
#pragma unroll
    for (int it = 0; it < 4; ++it) {
      const int c = it * 256 + tid;
      const int r = c >> 3, ko = (c & 7) << 3;
      load_lds16(Bt + (size_t)(col0 + r) * Cn + k0 + ko, &Bs[c * 8]);
    }
    __syncthreads();
#pragma unroll
    for (int ks = 0; ks < 2; ++ks) {
      bf16x8 af[4], bfr[4];
#pragma unroll
      for (int mi = 0; mi < 4; ++mi)
        af[mi] = *(const bf16x8*)&As[(wm * 64 + mi * 16 + lr) * 64 + ks * 32 + lg * 8];
#pragma unroll
      for (int ni = 0; ni < 4; ++ni)
        bfr[ni] = *(const bf16x8*)&Bs[(wn * 64 + ni * 16 + lr) * 64 + ks * 32 + lg * 8];
#pragma unroll
      for (int mi = 0; mi < 4; ++mi)
#pragma unroll
        for (int ni = 0; ni < 4; ++ni)
          acc[mi][ni] = MFMA16(af[mi], bfr[ni], acc[mi][ni]);
    }
    __syncthreads();
  }
}

// ---------------------------------------------------------------------------
// QKV fused projections: z=0 -> Q (heads, pre-scaled), z=1 -> K (heads),
// z=2 -> V^T [B,H,D,T]. Grid (8, 64, 3).
// ---------------------------------------------------------------------------
__global__ __launch_bounds__(256, 2) void qkv_gemm_k(
    const unsigned short* __restrict__ A,
    const unsigned short* __restrict__ Wq, const unsigned short* __restrict__ Wk,
    const unsigned short* __restrict__ Wv,
    const float* __restrict__ bq, const float* __restrict__ bk,
    const float* __restrict__ bv,
    unsigned short* __restrict__ Qo, unsigned short* __restrict__ Ko,
    unsigned short* __restrict__ Vo) {
  __shared__ unsigned short As[128 * 64];
  __shared__ unsigned short Bs[128 * 64];
  const int z = blockIdx.z;
  const unsigned short* Bt = (z == 0) ? Wq : (z == 1) ? Wk : Wv;
  const float* bias = (z == 0) ? bq : (z == 1) ? bk : bv;
  unsigned short* out = (z == 0) ? Qo : (z == 1) ? Ko : Vo;
  const float scale = (z == 0) ? kQScale : 1.0f;

  const int row0 = blockIdx.y * 128, col0 = blockIdx.x * 128;
  const f32x4 fz = {0.f, 0.f, 0.f, 0.f};
  f32x4 acc[4][4];
#pragma unroll
  for (int i = 0; i < 4; ++i)
#pragma unroll
    for (int j = 0; j < 4; ++j) acc[i][j] = fz;

  gemm_core(A, Bt, row0, col0, As, Bs, acc);

  const int lane = threadIdx.x & 63, w = threadIdx.x >> 6;
  const int wm = w >> 1, wn = w & 1;
  const int lr = lane & 15, lg = lane >> 4;
#pragma unroll
  for (int mi = 0; mi < 4; ++mi) {
#pragma unroll
    for (int ni = 0; ni < 4; ++ni) {
      const int col = col0 + wn * 64 + ni * 16 + lr;
      const float bv_ = bias[col];
      const int h = col >> 6, d = col & 63;
#pragma unroll
      for (int r = 0; r < 4; ++r) {
        const int row = row0 + wm * 64 + mi * 16 + lg * 4 + r;
        const float val = (acc[mi][ni][r] + bv_) * scale;
        const int b = row >> 11, t = row & (Tn - 1);
        if (z == 2) {
          out[(((size_t)b * Hn + h) * Dn + d) * Tn + t] = f2bf(val);
        } else {
          out[((((size_t)b * Hn + h) * Tn + t) << 6) + d] = f2bf(val);
        }
      }
    }
  }
}

// ---------------------------------------------------------------------------
// Output projection: fp32 out = Yb @ Wpt^T + bp
// ---------------------------------------------------------------------------
__global__ __launch_bounds__(256, 2) void proj_gemm_k(
    const unsigned short* __restrict__ A, const unsigned short* __restrict__ Bt,
    const float* __restrict__ bias, float* __restrict__ out) {
  __shared__ unsigned short As[128 * 64];
  __shared__ unsigned short Bs[128 * 64];
  const int row0 = blockIdx.y * 128, col0 = blockIdx.x * 128;
  const f32x4 fz = {0.f, 0.f, 0.f, 0.f};
  f32x4 acc[4][4];
#pragma unroll
  for (int i = 0; i < 4; ++i)
#pragma unroll
    for (int j = 0; j < 4; ++j) acc[i][j] = fz;

  gemm_core(A, Bt, row0, col0, As, Bs, acc);

  const int lane = threadIdx.x & 63, w = threadIdx.x >> 6;
  const int wm = w >> 1, wn = w & 1;
  const int lr = lane & 15, lg = lane >> 4;
#pragma unroll
  for (int mi = 0; mi < 4; ++mi) {
#pragma unroll
    for (int ni = 0; ni < 4; ++ni) {
      const int col = col0 + wn * 64 + ni * 16 + lr;
      const float bv_ = bias[col];
#pragma unroll
      for (int r = 0; r < 4; ++r) {
        const int row = row0 + wm * 64 + mi * 16 + lg * 4 + r;
        out[(size_t)row * Cn + col] = acc[mi][ni][r] + bv_;
      }
    }
  }
}

// ---------------------------------------------------------------------------
// Flash attention, bf16 MFMA, swapped-QK^T softmax (one q per lane).
// Q (pre-scaled by 0.125*log2e), K: [B,H,T,D]; Vt: [B,H,D,T]; Y: [B,T,C].
// Grid (32, 64), qt reversed (LPT). 4 waves; wave w owns q-rows w*16..+15.
// LDS tiles XOR-swizzled at 16B-chunk granularity: phys = log ^ (row & 7).
// ---------------------------------------------------------------------------
__global__ __launch_bounds__(256, 4) void attn_mfma_k(
    const unsigned short* __restrict__ Q, const unsigned short* __restrict__ K,
    const unsigned short* __restrict__ Vt, unsigned short* __restrict__ Y) {
  __shared__ unsigned short Ks[2][64 * 64];
  __shared__ unsigned short Vs[2][64 * 64];   // V^T tile: [d][key]
  __shared__ unsigned short Ps[4][16 * 64];   // per-wave P: [q][key]
  const int tid = threadIdx.x, lane = tid & 63, w = tid >> 6;
  const int lr = lane & 15, lg = lane >> 4;
  const int qt = (int)gridDim.x - 1 - blockIdx.x;  // heavy blocks first
  const int bh = blockIdx.y;
  const size_t base = (size_t)bh * Tn * Dn;

  // Q fragment; used as the B operand of mfma(K, Q): B[k=d][n=q],
  // n = lane&15, k = (lane>>4)*8 + j  -> same registers as an A fragment.
  bf16x8 qf[2];
  const int qrow = qt * 64 + w * 16 + lr;   // this lane's q (global)
#pragma unroll
  for (int ks = 0; ks < 2; ++ks)
    qf[ks] = *(const bf16x8*)&Q[base + (size_t)qrow * Dn + ks * 32 + lg * 8];

  // stage K tile [key][d] and V^T tile [d][key] with pre-swizzled source
  auto stage = [&](int buf, int kt) {
#pragma unroll
    for (int it = 0; it < 2; ++it) {
      const int c = it * 256 + tid;
      const int r = c >> 3;
      const int lc = (c & 7) ^ (r & 7);
      load_lds16(K + base + (size_t)(kt * 64 + r) * Dn + lc * 8, &Ks[buf][c * 8]);
      load_lds16(Vt + base + (size_t)r * Tn + kt * 64 + lc * 8, &Vs[buf][c * 8]);
    }
  };

  const f32x4 fz = {0.f, 0.f, 0.f, 0.f};
  f32x4 oacc[4];
#pragma unroll
  for (int i = 0; i < 4; ++i) oacc[i] = fz;
  float m_run = -1e30f, l_run = 0.f;

  stage(0, 0);
  asm volatile("s_waitcnt vmcnt(0)" ::: "memory");
  __syncthreads();
  int cur = 0;

  for (int kt = 0; kt <= qt; ++kt) {
    if (kt < qt) stage(cur ^ 1, kt + 1);  // prefetch next tile (other buffer)

    // S^T = K . Q^T : 4 key sub-tiles; D[row=key, col=q], col = lane&15.
    f32x4 s[4];
#pragma unroll
    for (int ni = 0; ni < 4; ++ni) s[ni] = fz;
#pragma unroll
    for (int ni = 0; ni < 4; ++ni)
#pragma unroll
      for (int ks = 0; ks < 2; ++ks) {
        const bf16x8 kf = *(const bf16x8*)
            &Ks[cur][(ni * 16 + lr) * 64 + (((ks * 4 + lg) ^ (lr & 7)) << 3)];
        s[ni] = MFMA16(kf, qf[ks], s[ni]);
      }

    // lane's S elements: key = kt*64 + ni*16 + lg*4 + r, all for q = qrow.
    const bool diag = (kt == qt);
    float sv[4][4];
#pragma unroll
    for (int ni = 0; ni < 4; ++ni)
#pragma unroll
      for (int r = 0; r < 4; ++r) {
        float v = s[ni][r];
        if (diag) {
          const int gk = kt * 64 + ni * 16 + lg * 4 + r;
          if (gk > qrow) v = -1e30f;
        }
        sv[ni][r] = v;
      }

    // per-q max: in-thread over 16, then across the 4 lane-groups
    float mm = -1e30f;
#pragma unroll
    for (int ni = 0; ni < 4; ++ni)
#pragma unroll
      for (int r = 0; r < 4; ++r) mm = fmaxf(mm, sv[ni][r]);
    mm = fmaxf(mm, __shfl_xor(mm, 16));
    mm = fmaxf(mm, __shfl_xor(mm, 32));
    const float mnew = fmaxf(m_run, mm);
    const float alpha = exp2f(m_run - mnew);
    m_run = mnew;

    float ps = 0.f;
    uint2 pw[4];
#pragma unroll
    for (int ni = 0; ni < 4; ++ni) {
      float p0 = exp2f(sv[ni][0] - mnew);
      float p1 = exp2f(sv[ni][1] - mnew);
      float p2 = exp2f(sv[ni][2] - mnew);
      float p3 = exp2f(sv[ni][3] - mnew);
      ps += (p0 + p1) + (p2 + p3);
      pw[ni].x = cvtpk_bf16(p0, p1);
      pw[ni].y = cvtpk_bf16(p2, p3);
    }
    ps += __shfl_xor(ps, 16);
    ps += __shfl_xor(ps, 32);
    l_run = l_run * alpha + ps;

    // store P into Ps[w] as [q=lr][key], 8B per ni, 16B-chunk swizzle
#pragma unroll
    for (int ni = 0; ni < 4; ++ni) {
      const int byte = lr * 128 + ((((ni * 2) + (lg >> 1)) ^ (lr & 7)) << 4) +
                       ((lg & 1) << 3);
      *(uint2*)((char*)&Ps[w][0] + byte) = pw[ni];
    }

    // rescale O by alpha (per q-row of this thread's accumulator)
#pragma unroll
    for (int i = 0; i < 4; ++i) {
      const float ai = __shfl(alpha, lg * 4 + i);
#pragma unroll
      for (int nd = 0; nd < 4; ++nd) oacc[nd][i] *= ai;
    }

    // O += P . V : A = P[q][key], B = V^T[d][key] (as B: col=d)
#pragma unroll
    for (int ks = 0; ks < 2; ++ks) {
      const bf16x8 pa = *(const bf16x8*)
          &Ps[w][lr * 64 + (((ks * 4 + lg) ^ (lr & 7)) << 3)];
#pragma unroll
      for (int nd = 0; nd < 4; ++nd) {
        const bf16x8 vf = *(const bf16x8*)
            &Vs[cur][(nd * 16 + lr) * 64 + (((ks * 4 + lg) ^ (lr & 7)) << 3)];
        oacc[nd] = MFMA16(pa, vf, oacc[nd]);
      }
    }

    asm volatile("s_waitcnt vmcnt(0)" ::: "memory");  // prefetch landed
    __syncthreads();
    cur ^= 1;
  }

  // epilogue -> Y [B,T,C] bf16
  const int b = bh >> 4, h = bh & 15;
#pragma unroll
  for (int i = 0; i < 4; ++i) {
    const float li = __shfl(l_run, lg * 4 + i);
    const float inv = 1.f / li;
    const int t = qt * 64 + w * 16 + lg * 4 + i;
#pragma unroll
    for (int nd = 0; nd < 4; ++nd) {
      const int d = nd * 16 + lr;
      Y[((size_t)b * Tn + t) * Cn + h * Dn + d] = f2bf(oacc[nd][i] * inv);
    }
  }
}

// ---------------------------------------------------------------------------
extern "C" void kernel_launch(void* const* d_in, const int* in_sizes, int n_in,
                              void* d_out, int out_size, void* d_ws, size_t ws_size,
                              hipStream_t stream) {
  const float* x  = (const float*)d_in[0];
  const float* Wq = (const float*)d_in[1];
  const float* bq = (const float*)d_in[2];
  const float* Wk = (const float*)d_in[3];
  const float* bk = (const float*)d_in[4];
  const float* Wv = (const float*)d_in[5];
  const float* bv = (const float*)d_in[6];
  const float* Wp = (const float*)d_in[7];
  const float* bp = (const float*)d_in[8];
  float* out = (float*)d_out;

  const size_t xe = (size_t)Bsz * Tn * Cn;  // 8,388,608
  const size_t we = (size_t)Cn * Cn;        // 1,048,576
  unsigned short* p = (unsigned short*)d_ws;
  unsigned short* xb  = p; p += xe;
  unsigned short* Wqt = p; p += we;
  unsigned short* Wkt = p; p += we;
  unsigned short* Wvt = p; p += we;
  unsigned short* Wpt = p; p += we;
  unsigned short* Qb  = p; p += xe;
  unsigned short* Kb  = p; p += xe;
  unsigned short* Vtb = p; p += xe;
  unsigned short* Yb  = p; p += xe;

  convert_x_k<<<dim3((int)(xe / 8 / 256)), dim3(256), 0, stream>>>(x, xb);
  transpose_w_k<<<dim3(16, 16, 4), dim3(256), 0, stream>>>(
      Wq, Wk, Wv, Wp, Wqt, Wkt, Wvt, Wpt);

  qkv_gemm_k<<<dim3(Cn / 128, (Bsz * Tn) / 128, 3), dim3(256), 0, stream>>>(
      xb, Wqt, Wkt, Wvt, bq, bk, bv, Qb, Kb, Vtb);

  attn_mfma_k<<<dim3(Tn / 64, Bsz * Hn), dim3(256), 0, stream>>>(Qb, Kb, Vtb, Yb);

  proj_gemm_k<<<dim3(Cn / 128, (Bsz * Tn) / 128), dim3(256), 0, stream>>>(
      Yb, Wpt, bp, out);
}